// Round 1
// baseline (1640.540 us; speedup 1.0000x reference)
//
#include <hip/hip_runtime.h>
#include <hip/hip_bf16.h>

#define NNODES 100000
#define NEDGES 1600000
#define FDIM 256
#define SCAN_CHUNK 1024
#define NB_SCAN ((NNODES + SCAN_CHUNK - 1) / SCAN_CHUNK)  // 98

// ---------------- CSR build ----------------

__global__ void k_count(const int* __restrict__ dst, int* __restrict__ cnt) {
  int i = blockIdx.x * blockDim.x + threadIdx.x;
  int stride = gridDim.x * blockDim.x;
  for (; i < NEDGES; i += stride) atomicAdd(&cnt[dst[i]], 1);
}

__global__ void k_scan_part(const int* __restrict__ cnt, int* __restrict__ partials) {
  __shared__ int red[256];
  int b = blockIdx.x, t = threadIdx.x;
  int base = b * SCAN_CHUNK + t * 4;
  int s = 0;
#pragma unroll
  for (int j = 0; j < 4; ++j) {
    int idx = base + j;
    if (idx < NNODES) s += cnt[idx];
  }
  red[t] = s;
  __syncthreads();
  for (int o = 128; o > 0; o >>= 1) {
    if (t < o) red[t] += red[t + o];
    __syncthreads();
  }
  if (t == 0) partials[b] = red[0];
}

__global__ void k_scan_partials(int* partials) {
  __shared__ int sc[128];
  int t = threadIdx.x;
  int v = (t < NB_SCAN) ? partials[t] : 0;
  sc[t] = v;
  __syncthreads();
  for (int o = 1; o < 128; o <<= 1) {
    int x = (t >= o) ? sc[t - o] : 0;
    __syncthreads();
    sc[t] += x;
    __syncthreads();
  }
  if (t < NB_SCAN) partials[t] = sc[t] - v;  // exclusive
}

__global__ void k_scan_final(const int* __restrict__ cnt, const int* __restrict__ partials,
                             int* __restrict__ rowptr, int* __restrict__ cursor) {
  __shared__ int sc[256];
  int b = blockIdx.x, t = threadIdx.x;
  int base = b * SCAN_CHUNK + t * 4;
  int c[4];
  int s = 0;
#pragma unroll
  for (int j = 0; j < 4; ++j) {
    int idx = base + j;
    c[j] = (idx < NNODES) ? cnt[idx] : 0;
    s += c[j];
  }
  int v = s;
  sc[t] = s;
  __syncthreads();
  for (int o = 1; o < 256; o <<= 1) {
    int x = (t >= o) ? sc[t - o] : 0;
    __syncthreads();
    sc[t] += x;
    __syncthreads();
  }
  int run = sc[t] - v + partials[b];
#pragma unroll
  for (int j = 0; j < 4; ++j) {
    int idx = base + j;
    if (idx < NNODES) {
      rowptr[idx] = run;
      cursor[idx] = run;
      run += c[j];
      if (idx == NNODES - 1) rowptr[NNODES] = run;
    }
  }
}

__global__ void k_fill(const int* __restrict__ src, const int* __restrict__ dst,
                       int* cursor, int* __restrict__ col) {
  int i = blockIdx.x * blockDim.x + threadIdx.x;
  int stride = gridDim.x * blockDim.x;
  for (; i < NEDGES; i += stride) {
    int d = dst[i];
    int p = atomicAdd(&cursor[d], 1);
    col[p] = src[i];
  }
}

// ---------------- conv1 aggregation fused with embedding lookup ----------------
// out[i] = x[i] + sum_{j in adj(i)} x[j], where x[n] = concat(emb_f[xcat[n][f]])
// One wave per node; lane l covers feature cols [4l, 4l+3]; field f = l>>4.

__global__ __launch_bounds__(256) void k_agg_embed(
    const int* __restrict__ xcat, const float* __restrict__ emb0,
    const float* __restrict__ emb1, const float* __restrict__ emb2,
    const float* __restrict__ emb3, const int* __restrict__ rowptr,
    const int* __restrict__ col, float* __restrict__ out) {
  int wid = (blockIdx.x * 256 + threadIdx.x) >> 6;
  int lane = threadIdx.x & 63;
  if (wid >= NNODES) return;
  int f = lane >> 4, e4 = lane & 15;
  const float4* tab = (const float4*)(f == 0 ? emb0 : f == 1 ? emb1 : f == 2 ? emb2 : emb3);

  int4 cat = ((const int4*)xcat)[wid];
  int c = (f == 0) ? cat.x : (f == 1) ? cat.y : (f == 2) ? cat.z : cat.w;
  float4 acc = tab[c * 16 + e4];

  int s = rowptr[wid], e = rowptr[wid + 1];
  for (int bb = s; bb < e; bb += 64) {
    int j = (bb + lane < e) ? col[bb + lane] : 0;
    int n = min(64, e - bb);
    for (int p = 0; p < n; ++p) {
      int jj = __shfl(j, p);
      int4 cj = ((const int4*)xcat)[jj];
      int cc = (f == 0) ? cj.x : (f == 1) ? cj.y : (f == 2) ? cj.z : cj.w;
      float4 v = tab[cc * 16 + e4];
      acc.x += v.x; acc.y += v.y; acc.z += v.z; acc.w += v.w;
    }
  }
  ((float4*)(out + (size_t)wid * FDIM))[lane] = acc;
}

// ---------------- generic aggregation (conv2) ----------------

__global__ __launch_bounds__(256) void k_agg(const float* __restrict__ xin,
                                             const int* __restrict__ rowptr,
                                             const int* __restrict__ col,
                                             float* __restrict__ out) {
  int wid = (blockIdx.x * 256 + threadIdx.x) >> 6;
  int lane = threadIdx.x & 63;
  if (wid >= NNODES) return;
  const float4* xrow = (const float4*)(xin + (size_t)wid * FDIM);
  float4 acc = xrow[lane];
  int s = rowptr[wid], e = rowptr[wid + 1];
  for (int bb = s; bb < e; bb += 64) {
    int j = (bb + lane < e) ? col[bb + lane] : 0;
    int n = min(64, e - bb);
    for (int p = 0; p < n; ++p) {
      int jj = __shfl(j, p);
      float4 v = ((const float4*)(xin + (size_t)jj * FDIM))[lane];
      acc.x += v.x; acc.y += v.y; acc.z += v.z; acc.w += v.w;
    }
  }
  ((float4*)(out + (size_t)wid * FDIM))[lane] = acc;
}

// ---------------- fused MLP: relu(in@Wa+ba)@Wb+bb [-> relu] -> LN ----------------
// 32 rows per block, 256 threads. All f32 (no fp32 MFMA on CDNA4 -> vector FMA).

template <int RELU_BEFORE_LN>
__global__ __launch_bounds__(256, 2) void k_mlp(
    const float* __restrict__ in, float* __restrict__ out,
    const float* __restrict__ Wa, const float* __restrict__ ba,
    const float* __restrict__ Wb, const float* __restrict__ bb,
    const float* __restrict__ gam, const float* __restrict__ bet) {
  __shared__ float sIn[32 * FDIM];
  __shared__ float sMid[32 * FDIM];
  __shared__ float sM[32], sR[32];
  const int tid = threadIdx.x;
  const size_t rowbase = (size_t)blockIdx.x * 32;

  // stage input tile
  {
    const float4* g4 = (const float4*)(in + rowbase * FDIM);
    float4* s4 = (float4*)sIn;
    for (int idx = tid; idx < 32 * 64; idx += 256) s4[idx] = g4[idx];
  }
  __syncthreads();

  const int rg = tid >> 5;  // 0..7 (4 rows each)
  const int ct = tid & 31;  // 0..31 (8 cols each)
  const int c0 = ct * 8;

  float acc[4][8];
  // GEMM1: relu(in @ Wa + ba)
#pragma unroll
  for (int rr = 0; rr < 4; ++rr)
#pragma unroll
    for (int j = 0; j < 8; ++j) acc[rr][j] = ba[c0 + j];
  {
    const float4* W4 = (const float4*)Wa;
#pragma unroll 4
    for (int k = 0; k < FDIM; ++k) {
      float4 w0 = W4[k * 64 + ct * 2];
      float4 w1 = W4[k * 64 + ct * 2 + 1];
#pragma unroll
      for (int rr = 0; rr < 4; ++rr) {
        float a = sIn[(rg * 4 + rr) * FDIM + k];
        acc[rr][0] = fmaf(a, w0.x, acc[rr][0]);
        acc[rr][1] = fmaf(a, w0.y, acc[rr][1]);
        acc[rr][2] = fmaf(a, w0.z, acc[rr][2]);
        acc[rr][3] = fmaf(a, w0.w, acc[rr][3]);
        acc[rr][4] = fmaf(a, w1.x, acc[rr][4]);
        acc[rr][5] = fmaf(a, w1.y, acc[rr][5]);
        acc[rr][6] = fmaf(a, w1.z, acc[rr][6]);
        acc[rr][7] = fmaf(a, w1.w, acc[rr][7]);
      }
    }
  }
#pragma unroll
  for (int rr = 0; rr < 4; ++rr)
#pragma unroll
    for (int j = 0; j < 8; ++j)
      sMid[(rg * 4 + rr) * FDIM + c0 + j] = fmaxf(acc[rr][j], 0.f);
  __syncthreads();

  // GEMM2: (mid @ Wb + bb)
#pragma unroll
  for (int rr = 0; rr < 4; ++rr)
#pragma unroll
    for (int j = 0; j < 8; ++j) acc[rr][j] = bb[c0 + j];
  {
    const float4* W4 = (const float4*)Wb;
#pragma unroll 4
    for (int k = 0; k < FDIM; ++k) {
      float4 w0 = W4[k * 64 + ct * 2];
      float4 w1 = W4[k * 64 + ct * 2 + 1];
#pragma unroll
      for (int rr = 0; rr < 4; ++rr) {
        float a = sMid[(rg * 4 + rr) * FDIM + k];
        acc[rr][0] = fmaf(a, w0.x, acc[rr][0]);
        acc[rr][1] = fmaf(a, w0.y, acc[rr][1]);
        acc[rr][2] = fmaf(a, w0.z, acc[rr][2]);
        acc[rr][3] = fmaf(a, w0.w, acc[rr][3]);
        acc[rr][4] = fmaf(a, w1.x, acc[rr][4]);
        acc[rr][5] = fmaf(a, w1.y, acc[rr][5]);
        acc[rr][6] = fmaf(a, w1.z, acc[rr][6]);
        acc[rr][7] = fmaf(a, w1.w, acc[rr][7]);
      }
    }
  }
  __syncthreads();  // sIn fully consumed by GEMM1 of all threads; safe to overwrite
#pragma unroll
  for (int rr = 0; rr < 4; ++rr)
#pragma unroll
    for (int j = 0; j < 8; ++j) {
      float v = acc[rr][j];
      if (RELU_BEFORE_LN) v = fmaxf(v, 0.f);
      sIn[(rg * 4 + rr) * FDIM + c0 + j] = v;
    }
  __syncthreads();

  // LayerNorm over each row of sIn
  {
    const int r = tid >> 3;  // 32 rows, 8 threads per row
    const int cg = tid & 7;
    const float4* s4r = (const float4*)(sIn + r * FDIM + cg * 32);
    float s1 = 0.f, s2 = 0.f;
#pragma unroll
    for (int i = 0; i < 8; ++i) {
      float4 v = s4r[i];
      s1 += v.x + v.y + v.z + v.w;
      s2 += v.x * v.x + v.y * v.y + v.z * v.z + v.w * v.w;
    }
#pragma unroll
    for (int o = 1; o < 8; o <<= 1) {
      s1 += __shfl_xor(s1, o);
      s2 += __shfl_xor(s2, o);
    }
    float m = s1 * (1.f / 256.f);
    float var = s2 * (1.f / 256.f) - m * m;
    float rstd = rsqrtf(var + 1e-5f);
    if (cg == 0) { sM[r] = m; sR[r] = rstd; }
  }
  __syncthreads();
  {
    const float4* s4 = (const float4*)sIn;
    const float4* g4 = (const float4*)gam;
    const float4* b4 = (const float4*)bet;
    float4* o4 = (float4*)(out + rowbase * FDIM);
    for (int idx = tid; idx < 32 * 64; idx += 256) {
      int row = idx >> 6, c4 = idx & 63;
      float4 v = s4[idx];
      float mm = sM[row], rs = sR[row];
      float4 gg = g4[c4], bb2 = b4[c4];
      float4 o;
      o.x = (v.x - mm) * rs * gg.x + bb2.x;
      o.y = (v.y - mm) * rs * gg.y + bb2.y;
      o.z = (v.z - mm) * rs * gg.z + bb2.z;
      o.w = (v.w - mm) * rs * gg.w + bb2.w;
      o4[idx] = o;
    }
  }
}

// ---------------- launch ----------------

extern "C" void kernel_launch(void* const* d_in, const int* in_sizes, int n_in,
                              void* d_out, int out_size, void* d_ws, size_t ws_size,
                              hipStream_t stream) {
  const int* xcat = (const int*)d_in[0];
  const int* edge = (const int*)d_in[1];
  const float* emb0 = (const float*)d_in[2];
  const float* emb1 = (const float*)d_in[3];
  const float* emb2 = (const float*)d_in[4];
  const float* emb3 = (const float*)d_in[5];
  const float* w1a = (const float*)d_in[6];
  const float* b1a = (const float*)d_in[7];
  const float* w1b = (const float*)d_in[8];
  const float* b1b = (const float*)d_in[9];
  const float* w2a = (const float*)d_in[10];
  const float* b2a = (const float*)d_in[11];
  const float* w2b = (const float*)d_in[12];
  const float* b2b = (const float*)d_in[13];
  const float* ln1g = (const float*)d_in[14];
  const float* ln1b = (const float*)d_in[15];
  const float* ln2g = (const float*)d_in[16];
  const float* ln2b = (const float*)d_in[17];
  float* outF = (float*)d_out;

  const int* srcP = edge;           // edge_index[0]
  const int* dstP = edge + NEDGES;  // edge_index[1]

  // workspace layout
  float* bufA = (float*)d_ws;                       // N*256 floats
  int* cnt = (int*)(bufA + (size_t)NNODES * FDIM);  // N
  int* rowptr = cnt + NNODES;                       // N+1
  int* cursor = rowptr + (NNODES + 1);              // N
  int* partials = cursor + NNODES;                  // 128
  int* col = partials + 128;                        // E

  // ---- CSR build ----
  hipMemsetAsync(cnt, 0, (size_t)NNODES * sizeof(int), stream);
  k_count<<<2048, 256, 0, stream>>>(dstP, cnt);
  k_scan_part<<<NB_SCAN, 256, 0, stream>>>(cnt, partials);
  k_scan_partials<<<1, 128, 0, stream>>>(partials);
  k_scan_final<<<NB_SCAN, 256, 0, stream>>>(cnt, partials, rowptr, cursor);
  k_fill<<<2048, 256, 0, stream>>>(srcP, dstP, cursor, col);

  // ---- conv1: fused embed + aggregate -> bufA ----
  k_agg_embed<<<NNODES / 4, 256, 0, stream>>>(xcat, emb0, emb1, emb2, emb3, rowptr, col, bufA);
  // ---- conv1 MLP + relu + LN -> d_out (holds h1) ----
  k_mlp<1><<<NNODES / 32, 256, 0, stream>>>(bufA, outF, w1a, b1a, w1b, b1b, ln1g, ln1b);
  // ---- conv2: aggregate h1 -> bufA ----
  k_agg<<<NNODES / 4, 256, 0, stream>>>(outF, rowptr, col, bufA);
  // ---- conv2 MLP + LN -> d_out ----
  k_mlp<0><<<NNODES / 32, 256, 0, stream>>>(bufA, outF, w2a, b2a, w2b, b2b, ln2g, ln2b);
}

// Round 2
// 995.138 us; speedup vs baseline: 1.6486x; 1.6486x over previous
//
#include <hip/hip_runtime.h>
#include <hip/hip_bf16.h>

#define NNODES 100000
#define NEDGES 1600000
#define FDIM 256
#define SCAN_CHUNK 1024
#define NB_SCAN ((NNODES + SCAN_CHUNK - 1) / SCAN_CHUNK)  // 98

typedef __bf16 bf16x8 __attribute__((ext_vector_type(8)));
typedef float f32x4 __attribute__((ext_vector_type(4)));

static __device__ inline __bf16 f2b(float f) { return (__bf16)f; }

// ---------------- CSR build ----------------

__global__ void k_count(const int* __restrict__ dst, int* __restrict__ cnt) {
  int i = blockIdx.x * blockDim.x + threadIdx.x;
  int stride = gridDim.x * blockDim.x;
  for (; i < NEDGES; i += stride) atomicAdd(&cnt[dst[i]], 1);
}

__global__ void k_scan_part(const int* __restrict__ cnt, int* __restrict__ partials) {
  __shared__ int red[256];
  int b = blockIdx.x, t = threadIdx.x;
  int base = b * SCAN_CHUNK + t * 4;
  int s = 0;
#pragma unroll
  for (int j = 0; j < 4; ++j) {
    int idx = base + j;
    if (idx < NNODES) s += cnt[idx];
  }
  red[t] = s;
  __syncthreads();
  for (int o = 128; o > 0; o >>= 1) {
    if (t < o) red[t] += red[t + o];
    __syncthreads();
  }
  if (t == 0) partials[b] = red[0];
}

__global__ void k_scan_partials(int* partials) {
  __shared__ int sc[128];
  int t = threadIdx.x;
  int v = (t < NB_SCAN) ? partials[t] : 0;
  sc[t] = v;
  __syncthreads();
  for (int o = 1; o < 128; o <<= 1) {
    int x = (t >= o) ? sc[t - o] : 0;
    __syncthreads();
    sc[t] += x;
    __syncthreads();
  }
  if (t < NB_SCAN) partials[t] = sc[t] - v;  // exclusive
}

__global__ void k_scan_final(const int* __restrict__ cnt, const int* __restrict__ partials,
                             int* __restrict__ rowptr, int* __restrict__ cursor) {
  __shared__ int sc[256];
  int b = blockIdx.x, t = threadIdx.x;
  int base = b * SCAN_CHUNK + t * 4;
  int c[4];
  int s = 0;
#pragma unroll
  for (int j = 0; j < 4; ++j) {
    int idx = base + j;
    c[j] = (idx < NNODES) ? cnt[idx] : 0;
    s += c[j];
  }
  int v = s;
  sc[t] = s;
  __syncthreads();
  for (int o = 1; o < 256; o <<= 1) {
    int x = (t >= o) ? sc[t - o] : 0;
    __syncthreads();
    sc[t] += x;
    __syncthreads();
  }
  int run = sc[t] - v + partials[b];
#pragma unroll
  for (int j = 0; j < 4; ++j) {
    int idx = base + j;
    if (idx < NNODES) {
      rowptr[idx] = run;
      cursor[idx] = run;
      run += c[j];
      if (idx == NNODES - 1) rowptr[NNODES] = run;
    }
  }
}

__global__ void k_fill(const int* __restrict__ src, const int* __restrict__ dst,
                       int* cursor, int* __restrict__ col) {
  int i = blockIdx.x * blockDim.x + threadIdx.x;
  int stride = gridDim.x * blockDim.x;
  for (; i < NEDGES; i += stride) {
    int d = dst[i];
    int p = atomicAdd(&cursor[d], 1);
    col[p] = src[i];
  }
}

// ---------------- weight prep: f32 [K][N] -> bf16 [N][K] (transposed) ----------------

__global__ void k_prep_w(const float* __restrict__ w1a, const float* __restrict__ w1b,
                         const float* __restrict__ w2a, const float* __restrict__ w2b,
                         __bf16* __restrict__ wt) {
  int mat = blockIdx.x >> 8;
  int n = blockIdx.x & 255;
  const float* W = (mat == 0) ? w1a : (mat == 1) ? w1b : (mat == 2) ? w2a : w2b;
  __bf16* dst = wt + (size_t)mat * 65536 + n * 256;
  int k = threadIdx.x;
  dst[k] = f2b(W[k * 256 + n]);
}

// ---------------- conv1 aggregation fused with embedding lookup ----------------

__global__ __launch_bounds__(256) void k_agg_embed(
    const int* __restrict__ xcat, const float* __restrict__ emb0,
    const float* __restrict__ emb1, const float* __restrict__ emb2,
    const float* __restrict__ emb3, const int* __restrict__ rowptr,
    const int* __restrict__ col, float* __restrict__ out) {
  int wid = (blockIdx.x * 256 + threadIdx.x) >> 6;
  int lane = threadIdx.x & 63;
  if (wid >= NNODES) return;
  int f = lane >> 4, e4 = lane & 15;
  const float4* tab = (const float4*)(f == 0 ? emb0 : f == 1 ? emb1 : f == 2 ? emb2 : emb3);

  int4 cat = ((const int4*)xcat)[wid];
  int c = (f == 0) ? cat.x : (f == 1) ? cat.y : (f == 2) ? cat.z : cat.w;
  float4 acc = tab[c * 16 + e4];

  int s = rowptr[wid], e = rowptr[wid + 1];
  for (int bb = s; bb < e; bb += 64) {
    int j = (bb + lane < e) ? col[bb + lane] : 0;
    int n = min(64, e - bb);
    for (int p = 0; p < n; ++p) {
      int jj = __shfl(j, p);
      int4 cj = ((const int4*)xcat)[jj];
      int cc = (f == 0) ? cj.x : (f == 1) ? cj.y : (f == 2) ? cj.z : cj.w;
      float4 v = tab[cc * 16 + e4];
      acc.x += v.x; acc.y += v.y; acc.z += v.z; acc.w += v.w;
    }
  }
  ((float4*)(out + (size_t)wid * FDIM))[lane] = acc;
}

// ---------------- generic aggregation (conv2) ----------------

__global__ __launch_bounds__(256) void k_agg(const float* __restrict__ xin,
                                             const int* __restrict__ rowptr,
                                             const int* __restrict__ col,
                                             float* __restrict__ out) {
  int wid = (blockIdx.x * 256 + threadIdx.x) >> 6;
  int lane = threadIdx.x & 63;
  if (wid >= NNODES) return;
  const float4* xrow = (const float4*)(xin + (size_t)wid * FDIM);
  float4 acc = xrow[lane];
  int s = rowptr[wid], e = rowptr[wid + 1];
  for (int bb = s; bb < e; bb += 64) {
    int j = (bb + lane < e) ? col[bb + lane] : 0;
    int n = min(64, e - bb);
    for (int p = 0; p < n; ++p) {
      int jj = __shfl(j, p);
      float4 v = ((const float4*)(xin + (size_t)jj * FDIM))[lane];
      acc.x += v.x; acc.y += v.y; acc.z += v.z; acc.w += v.w;
    }
  }
  ((float4*)(out + (size_t)wid * FDIM))[lane] = acc;
}

// ---------------- MFMA MLP: relu(in@Wa+ba)@Wb+bb [-> relu] -> LN ----------------
// BM=32 rows per block, 256 threads = 4 waves (wave w -> cols w*64..w*64+63).
// sA: [32][264] bf16 (full K=256 tile, 8-elem pad -> 2-way max LDS aliasing).
// sW: [256][40] bf16 (one 32-k slice of Wt[col][k], 80 B rows -> conflict-free).
// A/B fragments both read 8 contiguous k per lane (same packing for A and B ->
// correct for any internal hw k-permutation); C/D layout col=lane&15,
// row=(lane>>4)*4+reg (m89-verified).

#define BM 32
#define LDA 264
#define LDW 40

__device__ inline void gemm_tile(const __bf16* __restrict__ WtG, const __bf16* sA,
                                 __bf16* sW, f32x4 acc[2][4], int lane, int wid, int tid) {
#pragma unroll 1
  for (int ks = 0; ks < 8; ++ks) {
    // stage W k-slice: thread t = output col c, 32 contiguous k (64 B)
    {
      const bf16x8* g = (const bf16x8*)(WtG + tid * 256 + ks * 32);
      bf16x8* s = (bf16x8*)&sW[tid * LDW];
      bf16x8 w0 = g[0], w1 = g[1], w2 = g[2], w3 = g[3];
      s[0] = w0; s[1] = w1; s[2] = w2; s[3] = w3;
    }
    __syncthreads();
    const int ko = (lane >> 4) * 8;
    bf16x8 a0 = *(const bf16x8*)&sA[(lane & 15) * LDA + ks * 32 + ko];
    bf16x8 a1 = *(const bf16x8*)&sA[(16 + (lane & 15)) * LDA + ks * 32 + ko];
#pragma unroll
    for (int n = 0; n < 4; ++n) {
      bf16x8 b = *(const bf16x8*)&sW[(wid * 64 + n * 16 + (lane & 15)) * LDW + ko];
      acc[0][n] = __builtin_amdgcn_mfma_f32_16x16x32_bf16(a0, b, acc[0][n], 0, 0, 0);
      acc[1][n] = __builtin_amdgcn_mfma_f32_16x16x32_bf16(a1, b, acc[1][n], 0, 0, 0);
    }
    __syncthreads();
  }
}

template <int RELU_BEFORE_LN>
__global__ __launch_bounds__(256, 4) void k_mlp_mfma(
    const float* __restrict__ in, float* __restrict__ out,
    const __bf16* __restrict__ WtA, const float* __restrict__ ba,
    const __bf16* __restrict__ WtB, const float* __restrict__ bb,
    const float* __restrict__ gam, const float* __restrict__ bet) {
  __shared__ __bf16 sA[BM * LDA];
  __shared__ __bf16 sW[FDIM * LDW];
  __shared__ float sSum[BM], sSqs[BM];

  const int tid = threadIdx.x;
  const int lane = tid & 63;
  const int wid = tid >> 6;
  const size_t rowbase = (size_t)blockIdx.x * BM;

  if (tid < BM) { sSum[tid] = 0.f; sSqs[tid] = 0.f; }

  // ---- stage input tile f32 -> bf16 ----
  {
    int r = tid >> 3;
    int cb = (tid & 7) * 32;
    const float4* g = (const float4*)(in + (rowbase + (size_t)r) * FDIM + cb);
    bf16x8* s = (bf16x8*)&sA[r * LDA + cb];
#pragma unroll
    for (int i = 0; i < 4; ++i) {
      float4 x0 = g[2 * i], x1 = g[2 * i + 1];
      bf16x8 p;
      p[0] = f2b(x0.x); p[1] = f2b(x0.y); p[2] = f2b(x0.z); p[3] = f2b(x0.w);
      p[4] = f2b(x1.x); p[5] = f2b(x1.y); p[6] = f2b(x1.z); p[7] = f2b(x1.w);
      s[i] = p;
    }
  }
  // (first stage barrier inside gemm_tile covers this)

  f32x4 acc[2][4];
#pragma unroll
  for (int m = 0; m < 2; ++m)
#pragma unroll
    for (int n = 0; n < 4; ++n) acc[m][n] = (f32x4)0.f;

  // ---- GEMM1 ----
  gemm_tile(WtA, sA, sW, acc, lane, wid, tid);

  // epilogue 1: bias + relu -> H (bf16) overwrites sA
  {
    float bias[4];
#pragma unroll
    for (int n = 0; n < 4; ++n) bias[n] = ba[wid * 64 + n * 16 + (lane & 15)];
#pragma unroll
    for (int m = 0; m < 2; ++m)
#pragma unroll
      for (int n = 0; n < 4; ++n) {
        int c = wid * 64 + n * 16 + (lane & 15);
#pragma unroll
        for (int j = 0; j < 4; ++j) {
          int r = m * 16 + (lane >> 4) * 4 + j;
          float v = acc[m][n][j] + bias[n];
          v = fmaxf(v, 0.f);
          sA[r * LDA + c] = f2b(v);
        }
      }
  }
#pragma unroll
  for (int m = 0; m < 2; ++m)
#pragma unroll
    for (int n = 0; n < 4; ++n) acc[m][n] = (f32x4)0.f;

  // ---- GEMM2 ---- (first stage+sync inside fences the sA writes above)
  gemm_tile(WtB, sA, sW, acc, lane, wid, tid);

  // epilogue 2: bias (+relu) + LayerNorm -> global f32
  {
    float bias2[4], gm[4], bt[4];
#pragma unroll
    for (int n = 0; n < 4; ++n) {
      int c = wid * 64 + n * 16 + (lane & 15);
      bias2[n] = bb[c];
      gm[n] = gam[c];
      bt[n] = bet[c];
    }
#pragma unroll
    for (int m = 0; m < 2; ++m)
#pragma unroll
      for (int n = 0; n < 4; ++n)
#pragma unroll
        for (int j = 0; j < 4; ++j) {
          float v = acc[m][n][j] + bias2[n];
          if (RELU_BEFORE_LN) v = fmaxf(v, 0.f);
          acc[m][n][j] = v;
        }
    // row sums (each wave covers 64 of 256 cols; cross-wave via LDS atomics)
#pragma unroll
    for (int m = 0; m < 2; ++m)
#pragma unroll
      for (int j = 0; j < 4; ++j) {
        float s1 = acc[m][0][j] + acc[m][1][j] + acc[m][2][j] + acc[m][3][j];
        float s2 = acc[m][0][j] * acc[m][0][j] + acc[m][1][j] * acc[m][1][j] +
                   acc[m][2][j] * acc[m][2][j] + acc[m][3][j] * acc[m][3][j];
#pragma unroll
        for (int o = 1; o < 16; o <<= 1) {
          s1 += __shfl_xor(s1, o);
          s2 += __shfl_xor(s2, o);
        }
        if ((lane & 15) == 0) {
          int r = m * 16 + (lane >> 4) * 4 + j;
          atomicAdd(&sSum[r], s1);
          atomicAdd(&sSqs[r], s2);
        }
      }
    __syncthreads();
#pragma unroll
    for (int m = 0; m < 2; ++m)
#pragma unroll
      for (int j = 0; j < 4; ++j) {
        int r = m * 16 + (lane >> 4) * 4 + j;
        float mean = sSum[r] * (1.f / 256.f);
        float var = sSqs[r] * (1.f / 256.f) - mean * mean;
        float rstd = rsqrtf(var + 1e-5f);
#pragma unroll
        for (int n = 0; n < 4; ++n) {
          int c = wid * 64 + n * 16 + (lane & 15);
          out[(rowbase + r) * FDIM + c] = (acc[m][n][j] - mean) * rstd * gm[n] + bt[n];
        }
      }
  }
}

// ---------------- launch ----------------

extern "C" void kernel_launch(void* const* d_in, const int* in_sizes, int n_in,
                              void* d_out, int out_size, void* d_ws, size_t ws_size,
                              hipStream_t stream) {
  const int* xcat = (const int*)d_in[0];
  const int* edge = (const int*)d_in[1];
  const float* emb0 = (const float*)d_in[2];
  const float* emb1 = (const float*)d_in[3];
  const float* emb2 = (const float*)d_in[4];
  const float* emb3 = (const float*)d_in[5];
  const float* w1a = (const float*)d_in[6];
  const float* b1a = (const float*)d_in[7];
  const float* w1b = (const float*)d_in[8];
  const float* b1b = (const float*)d_in[9];
  const float* w2a = (const float*)d_in[10];
  const float* b2a = (const float*)d_in[11];
  const float* w2b = (const float*)d_in[12];
  const float* b2b = (const float*)d_in[13];
  const float* ln1g = (const float*)d_in[14];
  const float* ln1b = (const float*)d_in[15];
  const float* ln2g = (const float*)d_in[16];
  const float* ln2b = (const float*)d_in[17];
  float* outF = (float*)d_out;

  const int* srcP = edge;           // edge_index[0]
  const int* dstP = edge + NEDGES;  // edge_index[1]

  // workspace layout: bufA | col | rowptr | U, where U = {cnt,cursor,partials}
  // during CSR build, then overlaid by bf16 weights wt (prep runs after k_fill).
  float* bufA = (float*)d_ws;                           // N*256 f32
  int* col = (int*)(bufA + (size_t)NNODES * FDIM);      // E
  int* rowptr = col + NEDGES;                           // N+1 (padded to N+4)
  char* U = (char*)(rowptr + NNODES + 4);
  int* cnt = (int*)U;                                   // N
  int* cursor = cnt + NNODES;                           // N
  int* partials = cursor + NNODES;                      // 128
  __bf16* wt = (__bf16*)U;                              // 4 * 256 * 256 bf16

  // ---- CSR build ----
  hipMemsetAsync(cnt, 0, (size_t)NNODES * sizeof(int), stream);
  k_count<<<2048, 256, 0, stream>>>(dstP, cnt);
  k_scan_part<<<NB_SCAN, 256, 0, stream>>>(cnt, partials);
  k_scan_partials<<<1, 128, 0, stream>>>(partials);
  k_scan_final<<<NB_SCAN, 256, 0, stream>>>(cnt, partials, rowptr, cursor);
  k_fill<<<2048, 256, 0, stream>>>(srcP, dstP, cursor, col);

  // ---- weight prep (after k_fill: cnt/cursor dead, wt overlays them) ----
  k_prep_w<<<1024, 256, 0, stream>>>(w1a, w1b, w2a, w2b, wt);

  // ---- conv1: fused embed + aggregate -> bufA ----
  k_agg_embed<<<NNODES / 4, 256, 0, stream>>>(xcat, emb0, emb1, emb2, emb3, rowptr, col, bufA);
  // ---- conv1 MLP + relu + LN -> d_out (holds h1) ----
  k_mlp_mfma<1><<<NNODES / BM, 256, 0, stream>>>(bufA, outF, wt, b1a, wt + 65536, b1b, ln1g, ln1b);
  // ---- conv2: aggregate h1 -> bufA ----
  k_agg<<<NNODES / 4, 256, 0, stream>>>(outF, rowptr, col, bufA);
  // ---- conv2 MLP + LN -> d_out ----
  k_mlp_mfma<0><<<NNODES / BM, 256, 0, stream>>>(bufA, outF, wt + 131072, b2a, wt + 196608, b2b, ln2g, ln2b);
}

// Round 3
// 852.684 us; speedup vs baseline: 1.9240x; 1.1671x over previous
//
#include <hip/hip_runtime.h>
#include <hip/hip_bf16.h>

#define NNODES 100000
#define NEDGES 1600000
#define FDIM 256
#define SCAN_CHUNK 1024
#define NB_SCAN ((NNODES + SCAN_CHUNK - 1) / SCAN_CHUNK)  // 98

typedef __bf16 bf16x8 __attribute__((ext_vector_type(8)));
typedef __bf16 bf16x4 __attribute__((ext_vector_type(4)));
typedef float f32x4 __attribute__((ext_vector_type(4)));

static __device__ inline __bf16 f2b(float f) { return (__bf16)f; }

// ---------------- CSR build ----------------

__global__ void k_count(const int* __restrict__ dst, int* __restrict__ cnt) {
  int i = blockIdx.x * blockDim.x + threadIdx.x;
  int stride = gridDim.x * blockDim.x;
  for (; i < NEDGES; i += stride) atomicAdd(&cnt[dst[i]], 1);
}

__global__ void k_scan_part(const int* __restrict__ cnt, int* __restrict__ partials) {
  __shared__ int red[256];
  int b = blockIdx.x, t = threadIdx.x;
  int base = b * SCAN_CHUNK + t * 4;
  int s = 0;
#pragma unroll
  for (int j = 0; j < 4; ++j) {
    int idx = base + j;
    if (idx < NNODES) s += cnt[idx];
  }
  red[t] = s;
  __syncthreads();
  for (int o = 128; o > 0; o >>= 1) {
    if (t < o) red[t] += red[t + o];
    __syncthreads();
  }
  if (t == 0) partials[b] = red[0];
}

__global__ void k_scan_partials(int* partials) {
  __shared__ int sc[128];
  int t = threadIdx.x;
  int v = (t < NB_SCAN) ? partials[t] : 0;
  sc[t] = v;
  __syncthreads();
  for (int o = 1; o < 128; o <<= 1) {
    int x = (t >= o) ? sc[t - o] : 0;
    __syncthreads();
    sc[t] += x;
    __syncthreads();
  }
  if (t < NB_SCAN) partials[t] = sc[t] - v;  // exclusive
}

__global__ void k_scan_final(const int* __restrict__ cnt, const int* __restrict__ partials,
                             int* __restrict__ rowptr, int* __restrict__ cursor) {
  __shared__ int sc[256];
  int b = blockIdx.x, t = threadIdx.x;
  int base = b * SCAN_CHUNK + t * 4;
  int c[4];
  int s = 0;
#pragma unroll
  for (int j = 0; j < 4; ++j) {
    int idx = base + j;
    c[j] = (idx < NNODES) ? cnt[idx] : 0;
    s += c[j];
  }
  int v = s;
  sc[t] = s;
  __syncthreads();
  for (int o = 1; o < 256; o <<= 1) {
    int x = (t >= o) ? sc[t - o] : 0;
    __syncthreads();
    sc[t] += x;
    __syncthreads();
  }
  int run = sc[t] - v + partials[b];
#pragma unroll
  for (int j = 0; j < 4; ++j) {
    int idx = base + j;
    if (idx < NNODES) {
      rowptr[idx] = run;
      cursor[idx] = run;
      run += c[j];
      if (idx == NNODES - 1) rowptr[NNODES] = run;
    }
  }
}

__global__ void k_fill(const int* __restrict__ src, const int* __restrict__ dst,
                       int* cursor, int* __restrict__ col) {
  int i = blockIdx.x * blockDim.x + threadIdx.x;
  int stride = gridDim.x * blockDim.x;
  for (; i < NEDGES; i += stride) {
    int d = dst[i];
    int p = atomicAdd(&cursor[d], 1);
    col[p] = src[i];
  }
}

// ---------------- weight prep: f32 [K][N] -> bf16 [N][K] (transposed) ----------------

__global__ void k_prep_w(const float* __restrict__ w1a, const float* __restrict__ w1b,
                         const float* __restrict__ w2a, const float* __restrict__ w2b,
                         __bf16* __restrict__ wt) {
  int mat = blockIdx.x >> 8;
  int n = blockIdx.x & 255;
  const float* W = (mat == 0) ? w1a : (mat == 1) ? w1b : (mat == 2) ? w2a : w2b;
  __bf16* dst = wt + (size_t)mat * 65536 + n * 256;
  int k = threadIdx.x;
  dst[k] = f2b(W[k * 256 + n]);
}

// embeddings f32 -> bf16 (same layout, [field][1000][64])
__global__ void k_prep_emb(const float* __restrict__ e0, const float* __restrict__ e1,
                           const float* __restrict__ e2, const float* __restrict__ e3,
                           __bf16* __restrict__ embt) {
  int c = blockIdx.x;           // 0..999
  int f = threadIdx.x >> 6;     // 0..3
  int e = threadIdx.x & 63;     // 0..63
  const float* E = (f == 0) ? e0 : (f == 1) ? e1 : (f == 2) ? e2 : e3;
  embt[(size_t)f * 64000 + c * 64 + e] = f2b(E[c * 64 + e]);
}

// ---------------- conv1 aggregation fused with embedding lookup (bf16 tables) ----------------

__global__ __launch_bounds__(256) void k_agg_embed(
    const int* __restrict__ xcat, const __bf16* __restrict__ embt,
    const int* __restrict__ rowptr, const int* __restrict__ col,
    __bf16* __restrict__ out) {
  int wid = (blockIdx.x * 256 + threadIdx.x) >> 6;
  int lane = threadIdx.x & 63;
  if (wid >= NNODES) return;
  int f = lane >> 4, e4 = lane & 15;
  const bf16x4* tab = (const bf16x4*)(embt + (size_t)f * 64000);

  int4 cat = ((const int4*)xcat)[wid];
  int c = (f == 0) ? cat.x : (f == 1) ? cat.y : (f == 2) ? cat.z : cat.w;
  bf16x4 v0 = tab[c * 16 + e4];
  float acc0 = (float)v0[0], acc1 = (float)v0[1], acc2 = (float)v0[2], acc3 = (float)v0[3];

  int s = rowptr[wid], e = rowptr[wid + 1];
  for (int bb = s; bb < e; bb += 64) {
    int j = (bb + lane < e) ? col[bb + lane] : 0;
    int n = min(64, e - bb);
    for (int p = 0; p < n; ++p) {
      int jj = __shfl(j, p);
      int4 cj = ((const int4*)xcat)[jj];
      int cc = (f == 0) ? cj.x : (f == 1) ? cj.y : (f == 2) ? cj.z : cj.w;
      bf16x4 v = tab[cc * 16 + e4];
      acc0 += (float)v[0]; acc1 += (float)v[1]; acc2 += (float)v[2]; acc3 += (float)v[3];
    }
  }
  bf16x4 o;
  o[0] = f2b(acc0); o[1] = f2b(acc1); o[2] = f2b(acc2); o[3] = f2b(acc3);
  ((bf16x4*)(out + (size_t)wid * FDIM))[lane] = o;
}

// ---------------- generic aggregation (conv2, bf16 rows) ----------------

__global__ __launch_bounds__(256) void k_agg(const __bf16* __restrict__ xin,
                                             const int* __restrict__ rowptr,
                                             const int* __restrict__ col,
                                             __bf16* __restrict__ out) {
  int wid = (blockIdx.x * 256 + threadIdx.x) >> 6;
  int lane = threadIdx.x & 63;
  if (wid >= NNODES) return;
  bf16x4 sv = ((const bf16x4*)(xin + (size_t)wid * FDIM))[lane];
  float acc0 = (float)sv[0], acc1 = (float)sv[1], acc2 = (float)sv[2], acc3 = (float)sv[3];
  int s = rowptr[wid], e = rowptr[wid + 1];
  for (int bb = s; bb < e; bb += 64) {
    int j = (bb + lane < e) ? col[bb + lane] : 0;
    int n = min(64, e - bb);
    for (int p = 0; p < n; ++p) {
      int jj = __shfl(j, p);
      bf16x4 v = ((const bf16x4*)(xin + (size_t)jj * FDIM))[lane];
      acc0 += (float)v[0]; acc1 += (float)v[1]; acc2 += (float)v[2]; acc3 += (float)v[3];
    }
  }
  bf16x4 o;
  o[0] = f2b(acc0); o[1] = f2b(acc1); o[2] = f2b(acc2); o[3] = f2b(acc3);
  ((bf16x4*)(out + (size_t)wid * FDIM))[lane] = o;
}

// ---------------- MFMA MLP: relu(in@Wa+ba)@Wb+bb [-> relu] -> LN ----------------
// BM=32 rows per block, 256 threads = 4 waves (wave w -> cols w*64..w*64+63).
// sA: [32][264] bf16; sW: [256][40] bf16 (one 32-k slice of Wt[col][k]).
// A/B fragments both read 8 contiguous k per lane; C/D layout col=lane&15,
// row=(lane>>4)*4+reg (m89-verified).

#define BM 32
#define LDA 264
#define LDW 40

__device__ inline void gemm_tile(const __bf16* __restrict__ WtG, const __bf16* sA,
                                 __bf16* sW, f32x4 acc[2][4], int lane, int wid, int tid) {
#pragma unroll 1
  for (int ks = 0; ks < 8; ++ks) {
    // stage W k-slice: thread t = output col c, 32 contiguous k (64 B)
    {
      const bf16x8* g = (const bf16x8*)(WtG + tid * 256 + ks * 32);
      bf16x8* s = (bf16x8*)&sW[tid * LDW];
      bf16x8 w0 = g[0], w1 = g[1], w2 = g[2], w3 = g[3];
      s[0] = w0; s[1] = w1; s[2] = w2; s[3] = w3;
    }
    __syncthreads();
    const int ko = (lane >> 4) * 8;
    bf16x8 a0 = *(const bf16x8*)&sA[(lane & 15) * LDA + ks * 32 + ko];
    bf16x8 a1 = *(const bf16x8*)&sA[(16 + (lane & 15)) * LDA + ks * 32 + ko];
#pragma unroll
    for (int n = 0; n < 4; ++n) {
      bf16x8 b = *(const bf16x8*)&sW[(wid * 64 + n * 16 + (lane & 15)) * LDW + ko];
      acc[0][n] = __builtin_amdgcn_mfma_f32_16x16x32_bf16(a0, b, acc[0][n], 0, 0, 0);
      acc[1][n] = __builtin_amdgcn_mfma_f32_16x16x32_bf16(a1, b, acc[1][n], 0, 0, 0);
    }
    __syncthreads();
  }
}

template <int RELU_BEFORE_LN, int OUT_BF16>
__global__ __launch_bounds__(256, 4) void k_mlp_mfma(
    const __bf16* __restrict__ in, void* __restrict__ outp,
    const __bf16* __restrict__ WtA, const float* __restrict__ ba,
    const __bf16* __restrict__ WtB, const float* __restrict__ bb,
    const float* __restrict__ gam, const float* __restrict__ bet) {
  __shared__ __bf16 sA[BM * LDA];
  __shared__ __bf16 sW[FDIM * LDW];
  __shared__ float sSum[BM], sSqs[BM];

  const int tid = threadIdx.x;
  const int lane = tid & 63;
  const int wid = tid >> 6;
  const size_t rowbase = (size_t)blockIdx.x * BM;

  if (tid < BM) { sSum[tid] = 0.f; sSqs[tid] = 0.f; }

  // ---- stage input tile (already bf16) ----
  {
    int r = tid >> 3;
    int cb = (tid & 7) * 32;
    const bf16x8* g = (const bf16x8*)(in + (rowbase + (size_t)r) * FDIM + cb);
    bf16x8* s = (bf16x8*)&sA[r * LDA + cb];
    bf16x8 x0 = g[0], x1 = g[1], x2 = g[2], x3 = g[3];
    s[0] = x0; s[1] = x1; s[2] = x2; s[3] = x3;
  }
  // (first stage barrier inside gemm_tile covers this)

  f32x4 acc[2][4];
#pragma unroll
  for (int m = 0; m < 2; ++m)
#pragma unroll
    for (int n = 0; n < 4; ++n) acc[m][n] = (f32x4)0.f;

  // ---- GEMM1 ----
  gemm_tile(WtA, sA, sW, acc, lane, wid, tid);

  // epilogue 1: bias + relu -> H (bf16) overwrites sA
  {
    float bias[4];
#pragma unroll
    for (int n = 0; n < 4; ++n) bias[n] = ba[wid * 64 + n * 16 + (lane & 15)];
#pragma unroll
    for (int m = 0; m < 2; ++m)
#pragma unroll
      for (int n = 0; n < 4; ++n) {
        int c = wid * 64 + n * 16 + (lane & 15);
#pragma unroll
        for (int j = 0; j < 4; ++j) {
          int r = m * 16 + (lane >> 4) * 4 + j;
          float v = acc[m][n][j] + bias[n];
          v = fmaxf(v, 0.f);
          sA[r * LDA + c] = f2b(v);
        }
      }
  }
#pragma unroll
  for (int m = 0; m < 2; ++m)
#pragma unroll
    for (int n = 0; n < 4; ++n) acc[m][n] = (f32x4)0.f;

  // ---- GEMM2 ---- (first stage+sync inside fences the sA writes above)
  gemm_tile(WtB, sA, sW, acc, lane, wid, tid);

  // epilogue 2: bias (+relu) + LayerNorm -> global
  {
    float bias2[4], gm[4], bt[4];
#pragma unroll
    for (int n = 0; n < 4; ++n) {
      int c = wid * 64 + n * 16 + (lane & 15);
      bias2[n] = bb[c];
      gm[n] = gam[c];
      bt[n] = bet[c];
    }
#pragma unroll
    for (int m = 0; m < 2; ++m)
#pragma unroll
      for (int n = 0; n < 4; ++n)
#pragma unroll
        for (int j = 0; j < 4; ++j) {
          float v = acc[m][n][j] + bias2[n];
          if (RELU_BEFORE_LN) v = fmaxf(v, 0.f);
          acc[m][n][j] = v;
        }
    // row sums (each wave covers 64 of 256 cols; cross-wave via LDS atomics)
#pragma unroll
    for (int m = 0; m < 2; ++m)
#pragma unroll
      for (int j = 0; j < 4; ++j) {
        float s1 = acc[m][0][j] + acc[m][1][j] + acc[m][2][j] + acc[m][3][j];
        float s2 = acc[m][0][j] * acc[m][0][j] + acc[m][1][j] * acc[m][1][j] +
                   acc[m][2][j] * acc[m][2][j] + acc[m][3][j] * acc[m][3][j];
#pragma unroll
        for (int o = 1; o < 16; o <<= 1) {
          s1 += __shfl_xor(s1, o);
          s2 += __shfl_xor(s2, o);
        }
        if ((lane & 15) == 0) {
          int r = m * 16 + (lane >> 4) * 4 + j;
          atomicAdd(&sSum[r], s1);
          atomicAdd(&sSqs[r], s2);
        }
      }
    __syncthreads();
#pragma unroll
    for (int m = 0; m < 2; ++m)
#pragma unroll
      for (int j = 0; j < 4; ++j) {
        int r = m * 16 + (lane >> 4) * 4 + j;
        float mean = sSum[r] * (1.f / 256.f);
        float var = sSqs[r] * (1.f / 256.f) - mean * mean;
        float rstd = rsqrtf(var + 1e-5f);
#pragma unroll
        for (int n = 0; n < 4; ++n) {
          int c = wid * 64 + n * 16 + (lane & 15);
          float v = (acc[m][n][j] - mean) * rstd * gm[n] + bt[n];
          if (OUT_BF16)
            ((__bf16*)outp)[(rowbase + r) * FDIM + c] = f2b(v);
          else
            ((float*)outp)[(rowbase + r) * FDIM + c] = v;
        }
      }
  }
}

// ---------------- launch ----------------

extern "C" void kernel_launch(void* const* d_in, const int* in_sizes, int n_in,
                              void* d_out, int out_size, void* d_ws, size_t ws_size,
                              hipStream_t stream) {
  const int* xcat = (const int*)d_in[0];
  const int* edge = (const int*)d_in[1];
  const float* emb0 = (const float*)d_in[2];
  const float* emb1 = (const float*)d_in[3];
  const float* emb2 = (const float*)d_in[4];
  const float* emb3 = (const float*)d_in[5];
  const float* w1a = (const float*)d_in[6];
  const float* b1a = (const float*)d_in[7];
  const float* w1b = (const float*)d_in[8];
  const float* b1b = (const float*)d_in[9];
  const float* w2a = (const float*)d_in[10];
  const float* b2a = (const float*)d_in[11];
  const float* w2b = (const float*)d_in[12];
  const float* b2b = (const float*)d_in[13];
  const float* ln1g = (const float*)d_in[14];
  const float* ln1b = (const float*)d_in[15];
  const float* ln2g = (const float*)d_in[16];
  const float* ln2b = (const float*)d_in[17];
  float* outF = (float*)d_out;

  const int* srcP = edge;           // edge_index[0]
  const int* dstP = edge + NEDGES;  // edge_index[1]

  // workspace layout: bufA(bf16) | bufB(bf16) | col | rowptr | U
  // U = {cnt,cursor,partials} during CSR build, then overlaid by {wt, embt}
  // (prep kernels run after k_fill, when cnt/cursor/partials are dead).
  __bf16* bufA = (__bf16*)d_ws;                         // N*256 bf16 (agg out)
  __bf16* bufB = bufA + (size_t)NNODES * FDIM;          // N*256 bf16 (h1)
  int* col = (int*)(bufB + (size_t)NNODES * FDIM);      // E
  int* rowptr = col + NEDGES;                           // N+1 (padded to N+4)
  char* U = (char*)(rowptr + NNODES + 4);
  int* cnt = (int*)U;                                   // N
  int* cursor = cnt + NNODES;                           // N
  int* partials = cursor + NNODES;                      // 128
  __bf16* wt = (__bf16*)U;                              // 4 * 256 * 256 bf16
  __bf16* embt = wt + 262144;                           // 4 * 1000 * 64 bf16

  // ---- CSR build ----
  hipMemsetAsync(cnt, 0, (size_t)NNODES * sizeof(int), stream);
  k_count<<<2048, 256, 0, stream>>>(dstP, cnt);
  k_scan_part<<<NB_SCAN, 256, 0, stream>>>(cnt, partials);
  k_scan_partials<<<1, 128, 0, stream>>>(partials);
  k_scan_final<<<NB_SCAN, 256, 0, stream>>>(cnt, partials, rowptr, cursor);
  k_fill<<<2048, 256, 0, stream>>>(srcP, dstP, cursor, col);

  // ---- weight + embedding prep (cnt/cursor/partials dead now) ----
  k_prep_w<<<1024, 256, 0, stream>>>(w1a, w1b, w2a, w2b, wt);
  k_prep_emb<<<1000, 256, 0, stream>>>(emb0, emb1, emb2, emb3, embt);

  // ---- conv1: fused embed + aggregate -> bufA (bf16) ----
  k_agg_embed<<<NNODES / 4, 256, 0, stream>>>(xcat, embt, rowptr, col, bufA);
  // ---- conv1 MLP + relu + LN -> bufB (bf16 h1) ----
  k_mlp_mfma<1, 1><<<NNODES / BM, 256, 0, stream>>>(bufA, bufB, wt, b1a, wt + 65536, b1b, ln1g, ln1b);
  // ---- conv2: aggregate h1 -> bufA (bf16) ----
  k_agg<<<NNODES / 4, 256, 0, stream>>>(bufB, rowptr, col, bufA);
  // ---- conv2 MLP + LN -> d_out (f32) ----
  k_mlp_mfma<0, 0><<<NNODES / BM, 256, 0, stream>>>(bufA, outF, wt + 131072, b2a, wt + 196608, b2b, ln2g, ln2b);
}

// Round 6
// 753.816 us; speedup vs baseline: 2.1763x; 1.1312x over previous
//
#include <hip/hip_runtime.h>
#include <hip/hip_bf16.h>

#define NNODES 100000
#define NEDGES 1600000
#define FDIM 256
#define SCAN_CHUNK 1024
#define NB_SCAN ((NNODES + SCAN_CHUNK - 1) / SCAN_CHUNK)  // 98

typedef __bf16 bf16x8 __attribute__((ext_vector_type(8)));
typedef __bf16 bf16x4 __attribute__((ext_vector_type(4)));
typedef float f32x4 __attribute__((ext_vector_type(4)));

static __device__ inline __bf16 f2b(float f) { return (__bf16)f; }

// ---------------- CSR build ----------------

__global__ void k_count(const int* __restrict__ dst, int* __restrict__ cnt) {
  int i = blockIdx.x * blockDim.x + threadIdx.x;
  int stride = gridDim.x * blockDim.x;
  for (; i < NEDGES; i += stride) atomicAdd(&cnt[dst[i]], 1);
}

__global__ void k_scan_part(const int* __restrict__ cnt, int* __restrict__ partials) {
  __shared__ int red[256];
  int b = blockIdx.x, t = threadIdx.x;
  int base = b * SCAN_CHUNK + t * 4;
  int s = 0;
#pragma unroll
  for (int j = 0; j < 4; ++j) {
    int idx = base + j;
    if (idx < NNODES) s += cnt[idx];
  }
  red[t] = s;
  __syncthreads();
  for (int o = 128; o > 0; o >>= 1) {
    if (t < o) red[t] += red[t + o];
    __syncthreads();
  }
  if (t == 0) partials[b] = red[0];
}

__global__ void k_scan_partials(int* partials) {
  __shared__ int sc[128];
  int t = threadIdx.x;
  int v = (t < NB_SCAN) ? partials[t] : 0;
  sc[t] = v;
  __syncthreads();
  for (int o = 1; o < 128; o <<= 1) {
    int x = (t >= o) ? sc[t - o] : 0;
    __syncthreads();
    sc[t] += x;
    __syncthreads();
  }
  if (t < NB_SCAN) partials[t] = sc[t] - v;  // exclusive
}

__global__ void k_scan_final(const int* __restrict__ cnt, const int* __restrict__ partials,
                             int* __restrict__ rowptr, int* __restrict__ cursor) {
  __shared__ int sc[256];
  int b = blockIdx.x, t = threadIdx.x;
  int base = b * SCAN_CHUNK + t * 4;
  int c[4];
  int s = 0;
#pragma unroll
  for (int j = 0; j < 4; ++j) {
    int idx = base + j;
    c[j] = (idx < NNODES) ? cnt[idx] : 0;
    s += c[j];
  }
  int v = s;
  sc[t] = s;
  __syncthreads();
  for (int o = 1; o < 256; o <<= 1) {
    int x = (t >= o) ? sc[t - o] : 0;
    __syncthreads();
    sc[t] += x;
    __syncthreads();
  }
  int run = sc[t] - v + partials[b];
#pragma unroll
  for (int j = 0; j < 4; ++j) {
    int idx = base + j;
    if (idx < NNODES) {
      rowptr[idx] = run;
      cursor[idx] = run;
      run += c[j];
      if (idx == NNODES - 1) rowptr[NNODES] = run;
    }
  }
}

__global__ void k_fill(const int* __restrict__ src, const int* __restrict__ dst,
                       int* cursor, int* __restrict__ col) {
  int i = blockIdx.x * blockDim.x + threadIdx.x;
  int stride = gridDim.x * blockDim.x;
  for (; i < NEDGES; i += stride) {
    int d = dst[i];
    int p = atomicAdd(&cursor[d], 1);
    col[p] = src[i];
  }
}

// ---------------- weight prep: f32 [K][N] -> bf16 [N][K] (transposed) ----------------

__global__ void k_prep_w(const float* __restrict__ w1a, const float* __restrict__ w1b,
                         const float* __restrict__ w2a, const float* __restrict__ w2b,
                         __bf16* __restrict__ wt) {
  int mat = blockIdx.x >> 8;
  int n = blockIdx.x & 255;
  const float* W = (mat == 0) ? w1a : (mat == 1) ? w1b : (mat == 2) ? w2a : w2b;
  __bf16* dst = wt + (size_t)mat * 65536 + n * 256;
  int k = threadIdx.x;
  dst[k] = f2b(W[k * 256 + n]);
}

// embeddings f32 -> bf16 (same layout, [field][1000][64])
__global__ void k_prep_emb(const float* __restrict__ e0, const float* __restrict__ e1,
                           const float* __restrict__ e2, const float* __restrict__ e3,
                           __bf16* __restrict__ embt) {
  int c = blockIdx.x;           // 0..999
  int f = threadIdx.x >> 6;     // 0..3
  int e = threadIdx.x & 63;     // 0..63
  const float* E = (f == 0) ? e0 : (f == 1) ? e1 : (f == 2) ? e2 : e3;
  embt[(size_t)f * 64000 + c * 64 + e] = f2b(E[c * 64 + e]);
}

// ---------------- conv1 aggregation fused with embedding lookup ----------------
// One wave per node, 4 groups x 16 lanes; group g handles edges s+g, s+g+4, ...
// (4 independent load chains per wave, no cross-lane ops in divergent code).
// Lane (g,q) covers cols 16q..16q+15 (field f=q>>2); edge index loaded directly
// by all 16 lanes of the group (same address -> broadcast, L2-resident).

__global__ __launch_bounds__(256) void k_agg_embed(
    const int* __restrict__ xcat, const __bf16* __restrict__ embt,
    const int* __restrict__ rowptr, const int* __restrict__ col,
    __bf16* __restrict__ out) {
  int wid = (blockIdx.x * 256 + threadIdx.x) >> 6;
  int lane = threadIdx.x & 63;
  if (wid >= NNODES) return;
  const int g = lane >> 4, q = lane & 15;
  const int f = q >> 2;
  const __bf16* tab = embt + (size_t)f * 64000 + (q & 3) * 16;

  float acc[16];
  if (g == 0) {
    int cf = xcat[wid * 4 + f];
    const bf16x8* r = (const bf16x8*)(tab + cf * 64);
    bf16x8 v0 = r[0], v1 = r[1];
#pragma unroll
    for (int t = 0; t < 8; ++t) { acc[t] = (float)v0[t]; acc[8 + t] = (float)v1[t]; }
  } else {
#pragma unroll
    for (int t = 0; t < 16; ++t) acc[t] = 0.f;
  }

  int s = rowptr[wid], e = rowptr[wid + 1];
#pragma unroll 2
  for (int p = s + g; p < e; p += 4) {
    int jj = col[p];
    int cc = xcat[jj * 4 + f];
    const bf16x8* r = (const bf16x8*)(tab + cc * 64);
    bf16x8 v0 = r[0], v1 = r[1];
#pragma unroll
    for (int t = 0; t < 8; ++t) { acc[t] += (float)v0[t]; acc[8 + t] += (float)v1[t]; }
  }
  // cross-group reduce (all 64 lanes active here)
#pragma unroll
  for (int t = 0; t < 16; ++t) {
    acc[t] += __shfl_xor(acc[t], 16);
    acc[t] += __shfl_xor(acc[t], 32);
  }
  // lane (g,q) writes cols 16q+4g..+3  (static select; no runtime array index)
  float r0, r1, r2, r3;
  if (g == 0)      { r0 = acc[0];  r1 = acc[1];  r2 = acc[2];  r3 = acc[3];  }
  else if (g == 1) { r0 = acc[4];  r1 = acc[5];  r2 = acc[6];  r3 = acc[7];  }
  else if (g == 2) { r0 = acc[8];  r1 = acc[9];  r2 = acc[10]; r3 = acc[11]; }
  else             { r0 = acc[12]; r1 = acc[13]; r2 = acc[14]; r3 = acc[15]; }
  bf16x4 o;
  o[0] = f2b(r0); o[1] = f2b(r1); o[2] = f2b(r2); o[3] = f2b(r3);
  *((bf16x4*)(out + (size_t)wid * FDIM + q * 16 + g * 4)) = o;
}

// ---------------- generic aggregation (conv2, bf16 rows, 4-way edge ILP) ----------------

__global__ __launch_bounds__(256) void k_agg(const __bf16* __restrict__ xin,
                                             const int* __restrict__ rowptr,
                                             const int* __restrict__ col,
                                             __bf16* __restrict__ out) {
  int wid = (blockIdx.x * 256 + threadIdx.x) >> 6;
  int lane = threadIdx.x & 63;
  if (wid >= NNODES) return;
  const int g = lane >> 4, q = lane & 15;

  float acc[16];
  if (g == 0) {
    const bf16x8* r = (const bf16x8*)(xin + (size_t)wid * FDIM + q * 16);
    bf16x8 v0 = r[0], v1 = r[1];
#pragma unroll
    for (int t = 0; t < 8; ++t) { acc[t] = (float)v0[t]; acc[8 + t] = (float)v1[t]; }
  } else {
#pragma unroll
    for (int t = 0; t < 16; ++t) acc[t] = 0.f;
  }

  int s = rowptr[wid], e = rowptr[wid + 1];
#pragma unroll 2
  for (int p = s + g; p < e; p += 4) {
    int jj = col[p];
    const bf16x8* r = (const bf16x8*)(xin + (size_t)jj * FDIM + q * 16);
    bf16x8 v0 = r[0], v1 = r[1];
#pragma unroll
    for (int t = 0; t < 8; ++t) { acc[t] += (float)v0[t]; acc[8 + t] += (float)v1[t]; }
  }
#pragma unroll
  for (int t = 0; t < 16; ++t) {
    acc[t] += __shfl_xor(acc[t], 16);
    acc[t] += __shfl_xor(acc[t], 32);
  }
  float r0, r1, r2, r3;
  if (g == 0)      { r0 = acc[0];  r1 = acc[1];  r2 = acc[2];  r3 = acc[3];  }
  else if (g == 1) { r0 = acc[4];  r1 = acc[5];  r2 = acc[6];  r3 = acc[7];  }
  else if (g == 2) { r0 = acc[8];  r1 = acc[9];  r2 = acc[10]; r3 = acc[11]; }
  else             { r0 = acc[12]; r1 = acc[13]; r2 = acc[14]; r3 = acc[15]; }
  bf16x4 o;
  o[0] = f2b(r0); o[1] = f2b(r1); o[2] = f2b(r2); o[3] = f2b(r3);
  *((bf16x4*)(out + (size_t)wid * FDIM + q * 16 + g * 4)) = o;
}

// ---------------- MFMA MLP: relu(in@Wa+ba)@Wb+bb [-> relu] -> LN ----------------
// BM=32 rows per block, 256 threads = 4 waves (wave w -> cols w*64..w*64+63).
// sA: [32][264] bf16; sW: [256][40] bf16 (one 32-k slice of Wt[col][k]).
// A/B fragments both read 8 contiguous k per lane; C/D layout col=lane&15,
// row=(lane>>4)*4+reg (m89-verified).

#define BM 32
#define LDA 264
#define LDW 40

__device__ inline void gemm_tile(const __bf16* __restrict__ WtG, const __bf16* sA,
                                 __bf16* sW, f32x4 acc[2][4], int lane, int wid, int tid) {
#pragma unroll 1
  for (int ks = 0; ks < 8; ++ks) {
    // stage W k-slice: thread t = output col c, 32 contiguous k (64 B)
    {
      const bf16x8* g = (const bf16x8*)(WtG + tid * 256 + ks * 32);
      bf16x8* s = (bf16x8*)&sW[tid * LDW];
      bf16x8 w0 = g[0], w1 = g[1], w2 = g[2], w3 = g[3];
      s[0] = w0; s[1] = w1; s[2] = w2; s[3] = w3;
    }
    __syncthreads();
    const int ko = (lane >> 4) * 8;
    bf16x8 a0 = *(const bf16x8*)&sA[(lane & 15) * LDA + ks * 32 + ko];
    bf16x8 a1 = *(const bf16x8*)&sA[(16 + (lane & 15)) * LDA + ks * 32 + ko];
#pragma unroll
    for (int n = 0; n < 4; ++n) {
      bf16x8 b = *(const bf16x8*)&sW[(wid * 64 + n * 16 + (lane & 15)) * LDW + ko];
      acc[0][n] = __builtin_amdgcn_mfma_f32_16x16x32_bf16(a0, b, acc[0][n], 0, 0, 0);
      acc[1][n] = __builtin_amdgcn_mfma_f32_16x16x32_bf16(a1, b, acc[1][n], 0, 0, 0);
    }
    __syncthreads();
  }
}

template <int RELU_BEFORE_LN, int OUT_BF16>
__global__ __launch_bounds__(256, 4) void k_mlp_mfma(
    const __bf16* __restrict__ in, void* __restrict__ outp,
    const __bf16* __restrict__ WtA, const float* __restrict__ ba,
    const __bf16* __restrict__ WtB, const float* __restrict__ bb,
    const float* __restrict__ gam, const float* __restrict__ bet) {
  __shared__ __bf16 sA[BM * LDA];
  __shared__ __bf16 sW[FDIM * LDW];
  __shared__ float sSum[BM], sSqs[BM];

  const int tid = threadIdx.x;
  const int lane = tid & 63;
  const int wid = tid >> 6;
  const size_t rowbase = (size_t)blockIdx.x * BM;

  if (tid < BM) { sSum[tid] = 0.f; sSqs[tid] = 0.f; }

  // ---- stage input tile (already bf16) ----
  {
    int r = tid >> 3;
    int cb = (tid & 7) * 32;
    const bf16x8* g = (const bf16x8*)(in + (rowbase + (size_t)r) * FDIM + cb);
    bf16x8* s = (bf16x8*)&sA[r * LDA + cb];
    bf16x8 x0 = g[0], x1 = g[1], x2 = g[2], x3 = g[3];
    s[0] = x0; s[1] = x1; s[2] = x2; s[3] = x3;
  }
  // (first stage barrier inside gemm_tile covers this)

  f32x4 acc[2][4];
#pragma unroll
  for (int m = 0; m < 2; ++m)
#pragma unroll
    for (int n = 0; n < 4; ++n) acc[m][n] = (f32x4)0.f;

  // ---- GEMM1 ----
  gemm_tile(WtA, sA, sW, acc, lane, wid, tid);

  // epilogue 1: bias + relu -> H (bf16) overwrites sA
  {
    float bias[4];
#pragma unroll
    for (int n = 0; n < 4; ++n) bias[n] = ba[wid * 64 + n * 16 + (lane & 15)];
#pragma unroll
    for (int m = 0; m < 2; ++m)
#pragma unroll
      for (int n = 0; n < 4; ++n) {
        int c = wid * 64 + n * 16 + (lane & 15);
#pragma unroll
        for (int j = 0; j < 4; ++j) {
          int r = m * 16 + (lane >> 4) * 4 + j;
          float v = acc[m][n][j] + bias[n];
          v = fmaxf(v, 0.f);
          sA[r * LDA + c] = f2b(v);
        }
      }
  }
#pragma unroll
  for (int m = 0; m < 2; ++m)
#pragma unroll
    for (int n = 0; n < 4; ++n) acc[m][n] = (f32x4)0.f;

  // ---- GEMM2 ---- (first stage+sync inside fences the sA writes above)
  gemm_tile(WtB, sA, sW, acc, lane, wid, tid);

  // epilogue 2: bias (+relu) + LayerNorm -> global
  {
    float bias2[4], gm[4], bt[4];
#pragma unroll
    for (int n = 0; n < 4; ++n) {
      int c = wid * 64 + n * 16 + (lane & 15);
      bias2[n] = bb[c];
      gm[n] = gam[c];
      bt[n] = bet[c];
    }
#pragma unroll
    for (int m = 0; m < 2; ++m)
#pragma unroll
      for (int n = 0; n < 4; ++n)
#pragma unroll
        for (int j = 0; j < 4; ++j) {
          float v = acc[m][n][j] + bias2[n];
          if (RELU_BEFORE_LN) v = fmaxf(v, 0.f);
          acc[m][n][j] = v;
        }
    // row sums (each wave covers 64 of 256 cols; cross-wave via LDS atomics)
#pragma unroll
    for (int m = 0; m < 2; ++m)
#pragma unroll
      for (int j = 0; j < 4; ++j) {
        float s1 = acc[m][0][j] + acc[m][1][j] + acc[m][2][j] + acc[m][3][j];
        float s2 = acc[m][0][j] * acc[m][0][j] + acc[m][1][j] * acc[m][1][j] +
                   acc[m][2][j] * acc[m][2][j] + acc[m][3][j] * acc[m][3][j];
#pragma unroll
        for (int o = 1; o < 16; o <<= 1) {
          s1 += __shfl_xor(s1, o);
          s2 += __shfl_xor(s2, o);
        }
        if ((lane & 15) == 0) {
          int r = m * 16 + (lane >> 4) * 4 + j;
          atomicAdd(&sSum[r], s1);
          atomicAdd(&sSqs[r], s2);
        }
      }
    __syncthreads();
#pragma unroll
    for (int m = 0; m < 2; ++m)
#pragma unroll
      for (int j = 0; j < 4; ++j) {
        int r = m * 16 + (lane >> 4) * 4 + j;
        float mean = sSum[r] * (1.f / 256.f);
        float var = sSqs[r] * (1.f / 256.f) - mean * mean;
        float rstd = rsqrtf(var + 1e-5f);
#pragma unroll
        for (int n = 0; n < 4; ++n) {
          int c = wid * 64 + n * 16 + (lane & 15);
          float v = (acc[m][n][j] - mean) * rstd * gm[n] + bt[n];
          if (OUT_BF16)
            ((__bf16*)outp)[(rowbase + r) * FDIM + c] = f2b(v);
          else
            ((float*)outp)[(rowbase + r) * FDIM + c] = v;
        }
      }
  }
}

// ---------------- launch ----------------

extern "C" void kernel_launch(void* const* d_in, const int* in_sizes, int n_in,
                              void* d_out, int out_size, void* d_ws, size_t ws_size,
                              hipStream_t stream) {
  const int* xcat = (const int*)d_in[0];
  const int* edge = (const int*)d_in[1];
  const float* emb0 = (const float*)d_in[2];
  const float* emb1 = (const float*)d_in[3];
  const float* emb2 = (const float*)d_in[4];
  const float* emb3 = (const float*)d_in[5];
  const float* w1a = (const float*)d_in[6];
  const float* b1a = (const float*)d_in[7];
  const float* w1b = (const float*)d_in[8];
  const float* b1b = (const float*)d_in[9];
  const float* w2a = (const float*)d_in[10];
  const float* b2a = (const float*)d_in[11];
  const float* w2b = (const float*)d_in[12];
  const float* b2b = (const float*)d_in[13];
  const float* ln1g = (const float*)d_in[14];
  const float* ln1b = (const float*)d_in[15];
  const float* ln2g = (const float*)d_in[16];
  const float* ln2b = (const float*)d_in[17];
  float* outF = (float*)d_out;

  const int* srcP = edge;           // edge_index[0]
  const int* dstP = edge + NEDGES;  // edge_index[1]

  // workspace layout: bufA(bf16) | bufB(bf16) | col | rowptr | U
  // U = {cnt,cursor,partials} during CSR build, then overlaid by {wt, embt}
  // (prep kernels run after k_fill, when cnt/cursor/partials are dead).
  __bf16* bufA = (__bf16*)d_ws;                         // N*256 bf16 (agg out)
  __bf16* bufB = bufA + (size_t)NNODES * FDIM;          // N*256 bf16 (h1)
  int* col = (int*)(bufB + (size_t)NNODES * FDIM);      // E
  int* rowptr = col + NEDGES;                           // N+1 (padded to N+4)
  char* U = (char*)(rowptr + NNODES + 4);
  int* cnt = (int*)U;                                   // N
  int* cursor = cnt + NNODES;                           // N
  int* partials = cursor + NNODES;                      // 128
  __bf16* wt = (__bf16*)U;                              // 4 * 256 * 256 bf16
  __bf16* embt = wt + 262144;                           // 4 * 1000 * 64 bf16

  // ---- CSR build ----
  hipMemsetAsync(cnt, 0, (size_t)NNODES * sizeof(int), stream);
  k_count<<<2048, 256, 0, stream>>>(dstP, cnt);
  k_scan_part<<<NB_SCAN, 256, 0, stream>>>(cnt, partials);
  k_scan_partials<<<1, 128, 0, stream>>>(partials);
  k_scan_final<<<NB_SCAN, 256, 0, stream>>>(cnt, partials, rowptr, cursor);
  k_fill<<<2048, 256, 0, stream>>>(srcP, dstP, cursor, col);

  // ---- weight + embedding prep (cnt/cursor/partials dead now) ----
  k_prep_w<<<1024, 256, 0, stream>>>(w1a, w1b, w2a, w2b, wt);
  k_prep_emb<<<1000, 256, 0, stream>>>(emb0, emb1, emb2, emb3, embt);

  // ---- conv1: fused embed + aggregate -> bufA (bf16) ----
  k_agg_embed<<<NNODES / 4, 256, 0, stream>>>(xcat, embt, rowptr, col, bufA);
  // ---- conv1 MLP + relu + LN -> bufB (bf16 h1) ----
  k_mlp_mfma<1, 1><<<NNODES / BM, 256, 0, stream>>>(bufA, bufB, wt, b1a, wt + 65536, b1b, ln1g, ln1b);
  // ---- conv2: aggregate h1 -> bufA (bf16) ----
  k_agg<<<NNODES / 4, 256, 0, stream>>>(bufB, rowptr, col, bufA);
  // ---- conv2 MLP + LN -> d_out (f32) ----
  k_mlp_mfma<0, 0><<<NNODES / BM, 256, 0, stream>>>(bufA, outF, wt + 131072, b2a, wt + 196608, b2b, ln2g, ln2b);
}

// Round 7
// 710.261 us; speedup vs baseline: 2.3098x; 1.0613x over previous
//
#include <hip/hip_runtime.h>
#include <hip/hip_bf16.h>

#define NNODES 100000
#define NEDGES 1600000
#define FDIM 256
#define SCAN_CHUNK 1024
#define NB_SCAN ((NNODES + SCAN_CHUNK - 1) / SCAN_CHUNK)  // 98

typedef __bf16 bf16x8 __attribute__((ext_vector_type(8)));
typedef __bf16 bf16x4 __attribute__((ext_vector_type(4)));
typedef float f32x4 __attribute__((ext_vector_type(4)));

static __device__ inline __bf16 f2b(float f) { return (__bf16)f; }

// ---------------- CSR build ----------------

__global__ void k_count(const int* __restrict__ dst, int* __restrict__ cnt) {
  int i = blockIdx.x * blockDim.x + threadIdx.x;
  int stride = gridDim.x * blockDim.x;
  for (; i < NEDGES; i += stride) atomicAdd(&cnt[dst[i]], 1);
}

__global__ void k_scan_part(const int* __restrict__ cnt, int* __restrict__ partials) {
  __shared__ int red[256];
  int b = blockIdx.x, t = threadIdx.x;
  int base = b * SCAN_CHUNK + t * 4;
  int s = 0;
#pragma unroll
  for (int j = 0; j < 4; ++j) {
    int idx = base + j;
    if (idx < NNODES) s += cnt[idx];
  }
  red[t] = s;
  __syncthreads();
  for (int o = 128; o > 0; o >>= 1) {
    if (t < o) red[t] += red[t + o];
    __syncthreads();
  }
  if (t == 0) partials[b] = red[0];
}

__global__ void k_scan_partials(int* partials) {
  __shared__ int sc[128];
  int t = threadIdx.x;
  int v = (t < NB_SCAN) ? partials[t] : 0;
  sc[t] = v;
  __syncthreads();
  for (int o = 1; o < 128; o <<= 1) {
    int x = (t >= o) ? sc[t - o] : 0;
    __syncthreads();
    sc[t] += x;
    __syncthreads();
  }
  if (t < NB_SCAN) partials[t] = sc[t] - v;  // exclusive
}

__global__ void k_scan_final(const int* __restrict__ cnt, const int* __restrict__ partials,
                             int* __restrict__ rowptr, int* __restrict__ cursor) {
  __shared__ int sc[256];
  int b = blockIdx.x, t = threadIdx.x;
  int base = b * SCAN_CHUNK + t * 4;
  int c[4];
  int s = 0;
#pragma unroll
  for (int j = 0; j < 4; ++j) {
    int idx = base + j;
    c[j] = (idx < NNODES) ? cnt[idx] : 0;
    s += c[j];
  }
  int v = s;
  sc[t] = s;
  __syncthreads();
  for (int o = 1; o < 256; o <<= 1) {
    int x = (t >= o) ? sc[t - o] : 0;
    __syncthreads();
    sc[t] += x;
    __syncthreads();
  }
  int run = sc[t] - v + partials[b];
#pragma unroll
  for (int j = 0; j < 4; ++j) {
    int idx = base + j;
    if (idx < NNODES) {
      rowptr[idx] = run;
      cursor[idx] = run;
      run += c[j];
      if (idx == NNODES - 1) rowptr[NNODES] = run;
    }
  }
}

// XCD-sliced multi-pass fill: blockIdx&7 -> XCD slice of 12500 dst nodes;
// 4 sub-passes of 3125 nodes each. Every col[] line is written by one XCD
// within a ~200 KB window that stays L2-resident until fully written ->
// full-line writebacks instead of 64 B per edge.
__global__ void k_fill(const int* __restrict__ src, const int* __restrict__ dst,
                       int* cursor, int* __restrict__ col) {
  const int xcd = blockIdx.x & 7;
  const int tid = (blockIdx.x >> 3) * 256 + threadIdx.x;  // 0..65535
  const int stride = 256 * 256;
#pragma unroll 1
  for (int sp = 0; sp < 4; ++sp) {
    const int lo = xcd * 12500 + sp * 3125;
    const int hi = lo + 3125;
    for (int i = tid; i < NEDGES; i += stride) {
      int d = dst[i];
      if (d >= lo && d < hi) {
        int p = atomicAdd(&cursor[d], 1);
        col[p] = src[i];
      }
    }
  }
}

// ---------------- weight prep: f32 [K][N] -> bf16 [N][K] (transposed) ----------------

__global__ void k_prep_w(const float* __restrict__ w1a, const float* __restrict__ w1b,
                         const float* __restrict__ w2a, const float* __restrict__ w2b,
                         __bf16* __restrict__ wt) {
  int mat = blockIdx.x >> 8;
  int n = blockIdx.x & 255;
  const float* W = (mat == 0) ? w1a : (mat == 1) ? w1b : (mat == 2) ? w2a : w2b;
  __bf16* dst = wt + (size_t)mat * 65536 + n * 256;
  int k = threadIdx.x;
  dst[k] = f2b(W[k * 256 + n]);
}

// embeddings f32 -> bf16 (same layout, [field][1000][64])
__global__ void k_prep_emb(const float* __restrict__ e0, const float* __restrict__ e1,
                           const float* __restrict__ e2, const float* __restrict__ e3,
                           __bf16* __restrict__ embt) {
  int c = blockIdx.x;           // 0..999
  int f = threadIdx.x >> 6;     // 0..3
  int e = threadIdx.x & 63;     // 0..63
  const float* E = (f == 0) ? e0 : (f == 1) ? e1 : (f == 2) ? e2 : e3;
  embt[(size_t)f * 64000 + c * 64 + e] = f2b(E[c * 64 + e]);
}

// ---------------- conv1 aggregation fused with embedding lookup ----------------
// One wave per node, 4 groups x 16 lanes; group g handles edges s+g, s+g+4, ...
// (4 independent load chains per wave, no cross-lane ops in divergent code).

__global__ __launch_bounds__(256) void k_agg_embed(
    const int* __restrict__ xcat, const __bf16* __restrict__ embt,
    const int* __restrict__ rowptr, const int* __restrict__ col,
    __bf16* __restrict__ out) {
  int wid = (blockIdx.x * 256 + threadIdx.x) >> 6;
  int lane = threadIdx.x & 63;
  if (wid >= NNODES) return;
  const int g = lane >> 4, q = lane & 15;
  const int f = q >> 2;
  const __bf16* tab = embt + (size_t)f * 64000 + (q & 3) * 16;

  float acc[16];
  if (g == 0) {
    int cf = xcat[wid * 4 + f];
    const bf16x8* r = (const bf16x8*)(tab + cf * 64);
    bf16x8 v0 = r[0], v1 = r[1];
#pragma unroll
    for (int t = 0; t < 8; ++t) { acc[t] = (float)v0[t]; acc[8 + t] = (float)v1[t]; }
  } else {
#pragma unroll
    for (int t = 0; t < 16; ++t) acc[t] = 0.f;
  }

  int s = rowptr[wid], e = rowptr[wid + 1];
#pragma unroll 2
  for (int p = s + g; p < e; p += 4) {
    int jj = col[p];
    int cc = xcat[jj * 4 + f];
    const bf16x8* r = (const bf16x8*)(tab + cc * 64);
    bf16x8 v0 = r[0], v1 = r[1];
#pragma unroll
    for (int t = 0; t < 8; ++t) { acc[t] += (float)v0[t]; acc[8 + t] += (float)v1[t]; }
  }
  // cross-group reduce (all 64 lanes active here)
#pragma unroll
  for (int t = 0; t < 16; ++t) {
    acc[t] += __shfl_xor(acc[t], 16);
    acc[t] += __shfl_xor(acc[t], 32);
  }
  float r0, r1, r2, r3;
  if (g == 0)      { r0 = acc[0];  r1 = acc[1];  r2 = acc[2];  r3 = acc[3];  }
  else if (g == 1) { r0 = acc[4];  r1 = acc[5];  r2 = acc[6];  r3 = acc[7];  }
  else if (g == 2) { r0 = acc[8];  r1 = acc[9];  r2 = acc[10]; r3 = acc[11]; }
  else             { r0 = acc[12]; r1 = acc[13]; r2 = acc[14]; r3 = acc[15]; }
  bf16x4 o;
  o[0] = f2b(r0); o[1] = f2b(r1); o[2] = f2b(r2); o[3] = f2b(r3);
  *((bf16x4*)(out + (size_t)wid * FDIM + q * 16 + g * 4)) = o;
}

// ---------------- generic aggregation (conv2, bf16 rows, 4-way edge ILP) ----------------

__global__ __launch_bounds__(256) void k_agg(const __bf16* __restrict__ xin,
                                             const int* __restrict__ rowptr,
                                             const int* __restrict__ col,
                                             __bf16* __restrict__ out) {
  int wid = (blockIdx.x * 256 + threadIdx.x) >> 6;
  int lane = threadIdx.x & 63;
  if (wid >= NNODES) return;
  const int g = lane >> 4, q = lane & 15;

  float acc[16];
  if (g == 0) {
    const bf16x8* r = (const bf16x8*)(xin + (size_t)wid * FDIM + q * 16);
    bf16x8 v0 = r[0], v1 = r[1];
#pragma unroll
    for (int t = 0; t < 8; ++t) { acc[t] = (float)v0[t]; acc[8 + t] = (float)v1[t]; }
  } else {
#pragma unroll
    for (int t = 0; t < 16; ++t) acc[t] = 0.f;
  }

  int s = rowptr[wid], e = rowptr[wid + 1];
#pragma unroll 2
  for (int p = s + g; p < e; p += 4) {
    int jj = col[p];
    const bf16x8* r = (const bf16x8*)(xin + (size_t)jj * FDIM + q * 16);
    bf16x8 v0 = r[0], v1 = r[1];
#pragma unroll
    for (int t = 0; t < 8; ++t) { acc[t] += (float)v0[t]; acc[8 + t] += (float)v1[t]; }
  }
#pragma unroll
  for (int t = 0; t < 16; ++t) {
    acc[t] += __shfl_xor(acc[t], 16);
    acc[t] += __shfl_xor(acc[t], 32);
  }
  float r0, r1, r2, r3;
  if (g == 0)      { r0 = acc[0];  r1 = acc[1];  r2 = acc[2];  r3 = acc[3];  }
  else if (g == 1) { r0 = acc[4];  r1 = acc[5];  r2 = acc[6];  r3 = acc[7];  }
  else if (g == 2) { r0 = acc[8];  r1 = acc[9];  r2 = acc[10]; r3 = acc[11]; }
  else             { r0 = acc[12]; r1 = acc[13]; r2 = acc[14]; r3 = acc[15]; }
  bf16x4 o;
  o[0] = f2b(r0); o[1] = f2b(r1); o[2] = f2b(r2); o[3] = f2b(r3);
  *((bf16x4*)(out + (size_t)wid * FDIM + q * 16 + g * 4)) = o;
}

// ---------------- MFMA MLP: relu(in@Wa+ba)@Wb+bb [-> relu] -> LN ----------------
// BM=64 rows per block, 256 threads = 4 waves (wave w -> cols w*64..w*64+63).
// sA: [64][264] bf16; sW: [256][40] bf16 (one 32-k slice of Wt[col][k]).
// 256 MFMA per block vs 128 at BM=32 with identical staging/barrier cost.

#define BM 64
#define NBLK_MLP ((NNODES + BM - 1) / BM)  // 1563
#define LDA 264
#define LDW 40

__device__ inline void gemm_tile(const __bf16* __restrict__ WtG, const __bf16* sA,
                                 __bf16* sW, f32x4 acc[4][4], int lane, int wid, int tid) {
#pragma unroll 1
  for (int ks = 0; ks < 8; ++ks) {
    // stage W k-slice: thread t = output col c, 32 contiguous k (64 B)
    {
      const bf16x8* g = (const bf16x8*)(WtG + tid * 256 + ks * 32);
      bf16x8* s = (bf16x8*)&sW[tid * LDW];
      bf16x8 w0 = g[0], w1 = g[1], w2 = g[2], w3 = g[3];
      s[0] = w0; s[1] = w1; s[2] = w2; s[3] = w3;
    }
    __syncthreads();
    const int ko = (lane >> 4) * 8;
    const int ar = lane & 15;
    bf16x8 a0 = *(const bf16x8*)&sA[(ar +  0) * LDA + ks * 32 + ko];
    bf16x8 a1 = *(const bf16x8*)&sA[(ar + 16) * LDA + ks * 32 + ko];
    bf16x8 a2 = *(const bf16x8*)&sA[(ar + 32) * LDA + ks * 32 + ko];
    bf16x8 a3 = *(const bf16x8*)&sA[(ar + 48) * LDA + ks * 32 + ko];
#pragma unroll
    for (int n = 0; n < 4; ++n) {
      bf16x8 b = *(const bf16x8*)&sW[(wid * 64 + n * 16 + (lane & 15)) * LDW + ko];
      acc[0][n] = __builtin_amdgcn_mfma_f32_16x16x32_bf16(a0, b, acc[0][n], 0, 0, 0);
      acc[1][n] = __builtin_amdgcn_mfma_f32_16x16x32_bf16(a1, b, acc[1][n], 0, 0, 0);
      acc[2][n] = __builtin_amdgcn_mfma_f32_16x16x32_bf16(a2, b, acc[2][n], 0, 0, 0);
      acc[3][n] = __builtin_amdgcn_mfma_f32_16x16x32_bf16(a3, b, acc[3][n], 0, 0, 0);
    }
    __syncthreads();
  }
}

template <int RELU_BEFORE_LN, int OUT_BF16>
__global__ __launch_bounds__(256, 2) void k_mlp_mfma(
    const __bf16* __restrict__ in, void* __restrict__ outp,
    const __bf16* __restrict__ WtA, const float* __restrict__ ba,
    const __bf16* __restrict__ WtB, const float* __restrict__ bb,
    const float* __restrict__ gam, const float* __restrict__ bet) {
  __shared__ __bf16 sA[BM * LDA];
  __shared__ __bf16 sW[FDIM * LDW];
  __shared__ float sSum[BM], sSqs[BM];

  const int tid = threadIdx.x;
  const int lane = tid & 63;
  const int wid = tid >> 6;
  const size_t rowbase = (size_t)blockIdx.x * BM;

  if (tid < BM) { sSum[tid] = 0.f; sSqs[tid] = 0.f; }

  // ---- stage input tile (bf16); rows >= NNODES read in-ws garbage, never stored ----
  {
    int r = tid >> 2;
    int cb = (tid & 3) * 64;
    const bf16x8* g = (const bf16x8*)(in + (rowbase + (size_t)r) * FDIM + cb);
    bf16x8* s = (bf16x8*)&sA[r * LDA + cb];
#pragma unroll
    for (int i = 0; i < 8; ++i) s[i] = g[i];
  }
  // (first stage barrier inside gemm_tile covers this)

  f32x4 acc[4][4];
#pragma unroll
  for (int m = 0; m < 4; ++m)
#pragma unroll
    for (int n = 0; n < 4; ++n) acc[m][n] = (f32x4)0.f;

  // ---- GEMM1 ----
  gemm_tile(WtA, sA, sW, acc, lane, wid, tid);

  // epilogue 1: bias + relu -> H (bf16) overwrites sA
  {
    float bias[4];
#pragma unroll
    for (int n = 0; n < 4; ++n) bias[n] = ba[wid * 64 + n * 16 + (lane & 15)];
#pragma unroll
    for (int m = 0; m < 4; ++m)
#pragma unroll
      for (int n = 0; n < 4; ++n) {
        int c = wid * 64 + n * 16 + (lane & 15);
#pragma unroll
        for (int j = 0; j < 4; ++j) {
          int r = m * 16 + (lane >> 4) * 4 + j;
          float v = acc[m][n][j] + bias[n];
          v = fmaxf(v, 0.f);
          sA[r * LDA + c] = f2b(v);
        }
      }
  }
#pragma unroll
  for (int m = 0; m < 4; ++m)
#pragma unroll
    for (int n = 0; n < 4; ++n) acc[m][n] = (f32x4)0.f;

  // ---- GEMM2 ---- (first stage+sync inside fences the sA writes above)
  gemm_tile(WtB, sA, sW, acc, lane, wid, tid);

  // epilogue 2: bias (+relu) + LayerNorm -> global (guarded rows)
  {
    float bias2[4], gm[4], bt[4];
#pragma unroll
    for (int n = 0; n < 4; ++n) {
      int c = wid * 64 + n * 16 + (lane & 15);
      bias2[n] = bb[c];
      gm[n] = gam[c];
      bt[n] = bet[c];
    }
#pragma unroll
    for (int m = 0; m < 4; ++m)
#pragma unroll
      for (int n = 0; n < 4; ++n)
#pragma unroll
        for (int j = 0; j < 4; ++j) {
          float v = acc[m][n][j] + bias2[n];
          if (RELU_BEFORE_LN) v = fmaxf(v, 0.f);
          acc[m][n][j] = v;
        }
    // row sums (each wave covers 64 of 256 cols; cross-wave via LDS atomics)
#pragma unroll
    for (int m = 0; m < 4; ++m)
#pragma unroll
      for (int j = 0; j < 4; ++j) {
        float s1 = acc[m][0][j] + acc[m][1][j] + acc[m][2][j] + acc[m][3][j];
        float s2 = acc[m][0][j] * acc[m][0][j] + acc[m][1][j] * acc[m][1][j] +
                   acc[m][2][j] * acc[m][2][j] + acc[m][3][j] * acc[m][3][j];
#pragma unroll
        for (int o = 1; o < 16; o <<= 1) {
          s1 += __shfl_xor(s1, o);
          s2 += __shfl_xor(s2, o);
        }
        if ((lane & 15) == 0) {
          int r = m * 16 + (lane >> 4) * 4 + j;
          atomicAdd(&sSum[r], s1);
          atomicAdd(&sSqs[r], s2);
        }
      }
    __syncthreads();
#pragma unroll
    for (int m = 0; m < 4; ++m)
#pragma unroll
      for (int j = 0; j < 4; ++j) {
        int r = m * 16 + (lane >> 4) * 4 + j;
        if (rowbase + r >= NNODES) continue;
        float mean = sSum[r] * (1.f / 256.f);
        float var = sSqs[r] * (1.f / 256.f) - mean * mean;
        float rstd = rsqrtf(var + 1e-5f);
#pragma unroll
        for (int n = 0; n < 4; ++n) {
          int c = wid * 64 + n * 16 + (lane & 15);
          float v = (acc[m][n][j] - mean) * rstd * gm[n] + bt[n];
          if (OUT_BF16)
            ((__bf16*)outp)[(rowbase + r) * FDIM + c] = f2b(v);
          else
            ((float*)outp)[(rowbase + r) * FDIM + c] = v;
        }
      }
  }
}

// ---------------- launch ----------------

extern "C" void kernel_launch(void* const* d_in, const int* in_sizes, int n_in,
                              void* d_out, int out_size, void* d_ws, size_t ws_size,
                              hipStream_t stream) {
  const int* xcat = (const int*)d_in[0];
  const int* edge = (const int*)d_in[1];
  const float* emb0 = (const float*)d_in[2];
  const float* emb1 = (const float*)d_in[3];
  const float* emb2 = (const float*)d_in[4];
  const float* emb3 = (const float*)d_in[5];
  const float* w1a = (const float*)d_in[6];
  const float* b1a = (const float*)d_in[7];
  const float* w1b = (const float*)d_in[8];
  const float* b1b = (const float*)d_in[9];
  const float* w2a = (const float*)d_in[10];
  const float* b2a = (const float*)d_in[11];
  const float* w2b = (const float*)d_in[12];
  const float* b2b = (const float*)d_in[13];
  const float* ln1g = (const float*)d_in[14];
  const float* ln1b = (const float*)d_in[15];
  const float* ln2g = (const float*)d_in[16];
  const float* ln2b = (const float*)d_in[17];
  float* outF = (float*)d_out;

  const int* srcP = edge;           // edge_index[0]
  const int* dstP = edge + NEDGES;  // edge_index[1]

  // workspace layout: bufA(bf16) | bufB(bf16) | col | rowptr | U
  // U = {cnt,cursor,partials} during CSR build, then overlaid by {wt, embt}
  // (prep kernels run after k_fill, when cnt/cursor/partials are dead).
  __bf16* bufA = (__bf16*)d_ws;                         // N*256 bf16 (agg out)
  __bf16* bufB = bufA + (size_t)NNODES * FDIM;          // N*256 bf16 (h1)
  int* col = (int*)(bufB + (size_t)NNODES * FDIM);      // E
  int* rowptr = col + NEDGES;                           // N+1 (padded to N+4)
  char* U = (char*)(rowptr + NNODES + 4);
  int* cnt = (int*)U;                                   // N
  int* cursor = cnt + NNODES;                           // N
  int* partials = cursor + NNODES;                      // 128
  __bf16* wt = (__bf16*)U;                              // 4 * 256 * 256 bf16
  __bf16* embt = wt + 262144;                           // 4 * 1000 * 64 bf16

  // ---- CSR build ----
  hipMemsetAsync(cnt, 0, (size_t)NNODES * sizeof(int), stream);
  k_count<<<2048, 256, 0, stream>>>(dstP, cnt);
  k_scan_part<<<NB_SCAN, 256, 0, stream>>>(cnt, partials);
  k_scan_partials<<<1, 128, 0, stream>>>(partials);
  k_scan_final<<<NB_SCAN, 256, 0, stream>>>(cnt, partials, rowptr, cursor);
  k_fill<<<2048, 256, 0, stream>>>(srcP, dstP, cursor, col);

  // ---- weight + embedding prep (cnt/cursor/partials dead now) ----
  k_prep_w<<<1024, 256, 0, stream>>>(w1a, w1b, w2a, w2b, wt);
  k_prep_emb<<<1000, 256, 0, stream>>>(emb0, emb1, emb2, emb3, embt);

  // ---- conv1: fused embed + aggregate -> bufA (bf16) ----
  k_agg_embed<<<NNODES / 4, 256, 0, stream>>>(xcat, embt, rowptr, col, bufA);
  // ---- conv1 MLP + relu + LN -> bufB (bf16 h1) ----
  k_mlp_mfma<1, 1><<<NBLK_MLP, 256, 0, stream>>>(bufA, bufB, wt, b1a, wt + 65536, b1b, ln1g, ln1b);
  // ---- conv2: aggregate h1 -> bufA (bf16) ----
  k_agg<<<NNODES / 4, 256, 0, stream>>>(bufB, rowptr, col, bufA);
  // ---- conv2 MLP + LN -> d_out (f32) ----
  k_mlp_mfma<0, 0><<<NBLK_MLP, 256, 0, stream>>>(bufA, outF, wt + 131072, b2a, wt + 196608, b2b, ln2g, ln2b);
}